// Round 10
// baseline (403.930 us; speedup 1.0000x reference)
//
#include <hip/hip_runtime.h>
#include <hip/hip_bf16.h>

#define CDIM 384
#define NHEADS 12
#define HDIM 32
#define HIDDEN 1536
#define BBATCH 32
#define HH 28
#define WW 28
#define NTOK 784
#define BN (BBATCH * NTOK)   // 25088
#define LN_EPS 1e-5f
#define ATT_SCALE 0.17677669529663687f
#define YTILES 196           // BN / 128
#define PERXCD 25            // ceil(YTILES / 8)
#define YT2 98               // BN / 256
#define PERXCD2 13           // ceil(98 / 8)

typedef __hip_bfloat16 bf16;
typedef __attribute__((ext_vector_type(8))) short bf16x8;
typedef __attribute__((ext_vector_type(4))) float f32x4;

__device__ __forceinline__ void stf(float* p, float v) { *p = v; }
__device__ __forceinline__ void stf(bf16* p, float v) { *p = __float2bfloat16(v); }

__device__ __forceinline__ short f2bs(float v) {
    bf16 t = __float2bfloat16(v);
    return *reinterpret_cast<short*>(&t);
}

__device__ __forceinline__ float bf2f(unsigned short u) {
    return __uint_as_float(((unsigned)u) << 16);
}

// tanh-form GELU via sigmoid; max |diff| vs exact ~3e-4, well inside tolerance.
__device__ __forceinline__ float gelu_f(float x) {
    float u = x * (0.7978845608f + 0.0356774081f * x * x);
    float e = __expf(-2.f * u);
    return x / (1.f + e);
}

__device__ __forceinline__ void gload16(const void* g, void* l) {
    __builtin_amdgcn_global_load_lds(
        (const __attribute__((address_space(1))) unsigned int*)g,
        (__attribute__((address_space(3))) unsigned int*)l, 16, 0, 0);
}

// ---------------- fp32 -> bf16 weight conversion + cpe2 tap transpose, one launch ------
__global__ __launch_bounds__(256) void prep_k(
    const float* __restrict__ w0, const float* __restrict__ w1,
    const float* __restrict__ w2, const float* __restrict__ w3,
    bf16* __restrict__ dst, const float* __restrict__ cw,
    float* __restrict__ cwt)
{
    int blk = blockIdx.x;
    if (blk >= 6912) {                         // tail blocks: cpe2 (C,9)->(9,C)
        int i = (blk - 6912) * 256 + threadIdx.x;
        if (i < 9 * CDIM) {
            int k = i / CDIM, c = i % CDIM;
            cwt[i] = cw[c * 9 + k];
        }
        return;
    }
    int i = blk * 256 + threadIdx.x;           // 0..1769471, dst regions contiguous
    const float* src; int off;
    if (i < 442368)       { src = w0; off = i; }
    else if (i < 589824)  { src = w1; off = i - 442368; }
    else if (i < 1179648) { src = w2; off = i - 589824; }
    else                  { src = w3; off = i - 1179648; }
    dst[i] = __float2bfloat16(src[off]);
}

// ---------------- fused cpe1 + residual + transpose v3: lanes-along-c, 1 barrier -------
__global__ __launch_bounds__(256) void cpe1_tr_v3(
    const float* __restrict__ x, const float* __restrict__ w,
    const float* __restrict__ bias, float* __restrict__ xt)
{
    __shared__ float sm[32][130];   // 16.6 KB
    __shared__ float wls[32][10];   // per-block weight cache (stride 10 -> 2-way max)
    __shared__ float bls[32];
    int b = blockIdx.z;
    int n0 = blockIdx.y * 64;
    int c0 = blockIdx.x * 32;
    int tid = threadIdx.x;          // 256
    int nf0 = (n0 - 32) >> 2;       // window start in float4 units (may be negative)

    for (int i = tid; i < 288; i += 256) wls[i / 9][i % 9] = w[c0 * 9 + i];
    if (tid < 32) bls[tid] = bias[c0 + tid];

    const float4* xb = (const float4*)(x + ((size_t)b * CDIM + c0) * NTOK);
#pragma unroll
    for (int i = 0; i < 4; i++) {
        int q = tid + i * 256;      // 0..1023
        int row = q >> 5, c4 = q & 31;
        int nf = nf0 + c4;
        float4 v = {0.f, 0.f, 0.f, 0.f};
        if ((unsigned)nf < (NTOK >> 2)) v = xb[(size_t)row * (NTOK >> 2) + nf];
        float2* p = (float2*)&sm[row][c4 * 4];    // 8B-aligned (130*4=520 % 8 == 0)
        p[0] = make_float2(v.x, v.y);
        p[1] = make_float2(v.z, v.w);
    }
    __syncthreads();

    int c = tid & 31;
    int tsub = tid >> 5;            // 0..7
    float wr[9];
#pragma unroll
    for (int k = 0; k < 9; k++) wr[k] = wls[c][k];
    float bb = bls[c];
    const float* s = sm[c];
#pragma unroll
    for (int it = 0; it < 8; it++) {
        int tok = it * 8 + tsub;
        int n = n0 + tok;
        if (n < NTOK) {
            int h = n / WW, wc = n % WW;
            bool hm = h > 0, hp = h < HH - 1, wm = wc > 0, wpv = wc < WW - 1;
            int l = 32 + tok;
            float a = wr[4] * s[l];
            if (hm)        a += wr[1] * s[l - WW];
            if (hp)        a += wr[7] * s[l + WW];
            if (wm)        a += wr[3] * s[l - 1];
            if (wpv)       a += wr[5] * s[l + 1];
            if (hm && wm)  a += wr[0] * s[l - WW - 1];
            if (hm && wpv) a += wr[2] * s[l - WW + 1];
            if (hp && wm)  a += wr[6] * s[l + WW - 1];
            if (hp && wpv) a += wr[8] * s[l + WW + 1];
            xt[((size_t)b * NTOK + n) * CDIM + c0 + c] = s[l] + a + bb;
        }
    }
}

// ---------------- LN1: 32 lanes per token, float4 loads, ushort4 bf16 stores -----------
__global__ __launch_bounds__(256) void ln1_k(
    const float* __restrict__ in, const float* __restrict__ g,
    const float* __restrict__ b, bf16* __restrict__ out)
{
    int tid = threadIdx.x;
    int l = tid & 31;
    size_t tok = (size_t)blockIdx.x * 8 + (tid >> 5);
    const float4* row = (const float4*)(in + tok * CDIM);
    float4 v[3];
    float s = 0.f;
#pragma unroll
    for (int j = 0; j < 3; j++) {
        v[j] = row[l + j * 32];
        s += v[j].x + v[j].y + v[j].z + v[j].w;
    }
#pragma unroll
    for (int off = 16; off >= 1; off >>= 1) s += __shfl_xor(s, off);
    float mu = s * (1.f / CDIM);
    float q = 0.f;
#pragma unroll
    for (int j = 0; j < 3; j++) {
        float dx = v[j].x - mu, dy = v[j].y - mu;
        float dz = v[j].z - mu, dw = v[j].w - mu;
        q += dx * dx + dy * dy + dz * dz + dw * dw;
    }
#pragma unroll
    for (int off = 16; off >= 1; off >>= 1) q += __shfl_xor(q, off);
    float rs = rsqrtf(q * (1.f / CDIM) + LN_EPS);
    const float4* g4 = (const float4*)g;
    const float4* b4 = (const float4*)b;
    ushort4* o4 = (ushort4*)(out + tok * CDIM);
#pragma unroll
    for (int j = 0; j < 3; j++) {
        int idx = l + j * 32;
        float4 gv = g4[idx], bv = b4[idx];
        ushort4 r;
        r.x = (unsigned short)f2bs((v[j].x - mu) * rs * gv.x + bv.x);
        r.y = (unsigned short)f2bs((v[j].y - mu) * rs * gv.y + bv.y);
        r.z = (unsigned short)f2bs((v[j].z - mu) * rs * gv.z + bv.z);
        r.w = (unsigned short)f2bs((v[j].w - mu) * rs * gv.w + bv.w);
        o4[idx] = r;
    }
}

// ---------------- fused cpe2 + residual + LN2: 32 lanes per token, float4 --------------
__global__ __launch_bounds__(256) void cpe2_ln_fused(
    const float* __restrict__ xin, const float* __restrict__ wt,
    const float* __restrict__ cbias, const float* __restrict__ g,
    const float* __restrict__ b, float* __restrict__ x3,
    bf16* __restrict__ lnout)
{
    __shared__ float wts[9 * CDIM];
    int tid = threadIdx.x;
    for (int i = tid; i < 864; i += 256)
        ((float4*)wts)[i] = ((const float4*)wt)[i];
    __syncthreads();
    int l = tid & 31;
    size_t tok = (size_t)blockIdx.x * 8 + (tid >> 5);
    int n = (int)(tok % NTOK);
    int h = n / WW, wc = n % WW;
    bool hm = h > 0, hp = h < HH - 1, wm = wc > 0, wpv = wc < WW - 1;
    const float* row = xin + tok * CDIM;
    const float4* w4 = (const float4*)wts;
    float4 ctr[3], acc[3];
#pragma unroll
    for (int j = 0; j < 3; j++) {
        int idx = l + j * 32;
        ctr[j] = ((const float4*)row)[idx];
        float4 ww = w4[4 * 96 + idx];
        acc[j].x = ww.x * ctr[j].x; acc[j].y = ww.y * ctr[j].y;
        acc[j].z = ww.z * ctr[j].z; acc[j].w = ww.w * ctr[j].w;
    }
#define TAP(k, cond, dn)                                                     \
    if (cond) {                                                              \
        const float4* rp = (const float4*)(row + (dn) * CDIM);               \
        _Pragma("unroll")                                                    \
        for (int j = 0; j < 3; j++) {                                        \
            int idx = l + j * 32;                                            \
            float4 vv = rp[idx];                                             \
            float4 ww = w4[(k) * 96 + idx];                                  \
            acc[j].x = fmaf(ww.x, vv.x, acc[j].x);                           \
            acc[j].y = fmaf(ww.y, vv.y, acc[j].y);                           \
            acc[j].z = fmaf(ww.z, vv.z, acc[j].z);                           \
            acc[j].w = fmaf(ww.w, vv.w, acc[j].w);                           \
        }                                                                    \
    }
    TAP(0, hm && wm,   -WW - 1)
    TAP(1, hm,         -WW)
    TAP(2, hm && wpv,  -WW + 1)
    TAP(3, wm,         -1)
    TAP(5, wpv,        1)
    TAP(6, hp && wm,   WW - 1)
    TAP(7, hp,         WW)
    TAP(8, hp && wpv,  WW + 1)
#undef TAP
    float s = 0.f;
    float4 val[3];
    float4* x3r = (float4*)(x3 + tok * CDIM);
#pragma unroll
    for (int j = 0; j < 3; j++) {
        int idx = l + j * 32;
        float4 cb = ((const float4*)cbias)[idx];
        val[j].x = ctr[j].x + acc[j].x + cb.x;
        val[j].y = ctr[j].y + acc[j].y + cb.y;
        val[j].z = ctr[j].z + acc[j].z + cb.z;
        val[j].w = ctr[j].w + acc[j].w + cb.w;
        x3r[idx] = val[j];
        s += val[j].x + val[j].y + val[j].z + val[j].w;
    }
#pragma unroll
    for (int off = 16; off >= 1; off >>= 1) s += __shfl_xor(s, off);
    float mu = s * (1.f / CDIM);
    float q = 0.f;
#pragma unroll
    for (int j = 0; j < 3; j++) {
        float dx = val[j].x - mu, dy = val[j].y - mu;
        float dz = val[j].z - mu, dw = val[j].w - mu;
        q += dx * dx + dy * dy + dz * dz + dw * dw;
    }
#pragma unroll
    for (int off = 16; off >= 1; off >>= 1) q += __shfl_xor(q, off);
    float rs = rsqrtf(q * (1.f / CDIM) + LN_EPS);
    const float4* g4 = (const float4*)g;
    const float4* b4 = (const float4*)b;
    ushort4* o4 = (ushort4*)(lnout + tok * CDIM);
#pragma unroll
    for (int j = 0; j < 3; j++) {
        int idx = l + j * 32;
        float4 gv = g4[idx], bv = b4[idx];
        ushort4 r;
        r.x = (unsigned short)f2bs((val[j].x - mu) * rs * gv.x + bv.x);
        r.y = (unsigned short)f2bs((val[j].y - mu) * rs * gv.y + bv.y);
        r.z = (unsigned short)f2bs((val[j].z - mu) * rs * gv.z + bv.z);
        r.w = (unsigned short)f2bs((val[j].w - mu) * rs * gv.w + bv.w);
        o4[idx] = r;
    }
}

// ---------------- MFMA GEMM-256: 256x128 tile, BK=32, 8 waves, 48KB -> 3 blocks/CU -----
// Wall model (v1/v4/v8 measured): time ~ iters x (blocks/CU / resident) x 5.6K cyc.
// 128^2 fc1: 12 x 9.38/4 = 28 walls -> 66us. This tile: fc1 1176 blocks -> 12 x 4.59/3
// = 18.4 walls (x0.66); qkv 882 -> 13.8 (x0.65). Per-wave code IDENTICAL to v8 (4x4
// frags, 64 acc VGPR, verified 0-conflict swizzle, 2-phase loop). bf16 epilogue is
// wave-PRIVATE: each wave transposes its 64x64 through its own [32][68] slab in two
// sub-passes (17KB more LDS, no cross-wave barriers — avoids r7's serialized passes).
// Used for qkv+fc1 only (bf16-out, no RES); proj/fc2 stay on the proven 128^2 kernel.
template <int ACT, int K>
__global__ __launch_bounds__(512, 4) void gemm256(
    const short* __restrict__ Abf, const short* __restrict__ Bw,
    const float* __restrict__ bias, bf16* __restrict__ Co, int M, int NX)
{
    int id = blockIdx.x;
    int xcd = id & 7, slot_ = id >> 3;
    int yloc = slot_ / NX, xx = slot_ - yloc * NX;
    int y = xcd * PERXCD2 + yloc;
    if (y >= YT2) return;

    __shared__ __align__(16) short lds[24576];  // 48KB: 2 x (A 8192 | B 4096) shorts
    const int tid = threadIdx.x;
    const int wid = tid >> 6, lane = tid & 63;
    const int wr = wid >> 1, wc = wid & 1;      // 4x2 wave grid, each 64x64 out
    const int quad = lane >> 4, lr = lane & 15;
    const int r0 = y * 256, m0 = xx * 128;

    const int srow = lane >> 2;                      // 16 rows per gload round
    const int sg   = (lane & 3) ^ ((lane >> 3) & 3); // source colgroup g^((row>>1)&3)
    const short* gA = Abf + (size_t)(r0 + wid * 32 + srow) * K + sg * 8;
    const short* gB = Bw  + (size_t)(m0 + wid * 16 + srow) * K + sg * 8;

    auto stage = [&](int k0, int p) {
        short* lA = lds + p * 12288 + wid * 1024;       // wave stages A rows [w*32,+32)
        short* lB = lds + p * 12288 + 8192 + wid * 512; // and B rows [w*16,+16)
#pragma unroll
        for (int k = 0; k < 2; k++)
            gload16(gA + k0 + (size_t)k * 16 * K, lA + k * 512);
        gload16(gB + k0, lB);
    };

    const int slot = (quad ^ ((lr >> 1) & 3)) * 8;   // inverse swizzle (0 conflicts)
    int fA[4], fB[4];
#pragma unroll
    for (int i = 0; i < 4; i++) {
        fA[i] = (wr * 64 + i * 16 + lr) * 32 + slot;
        fB[i] = 8192 + (wc * 64 + i * 16 + lr) * 32 + slot;
    }

    f32x4 acc[4][4] = {};

    stage(0, 0);
    int p = 0;
    for (int k0 = 0; k0 < K; k0 += 32) {
        __syncthreads();
        if (k0 + 32 < K) stage(k0 + 32, p ^ 1);     // overlaps compute below
        const short* S = lds + p * 12288;
        bf16x8 av[4], bv[4];
#pragma unroll
        for (int i = 0; i < 4; i++) {
            av[i] = *(const bf16x8*)(S + fA[i]);
            bv[i] = *(const bf16x8*)(S + fB[i]);
        }
#pragma unroll
        for (int i = 0; i < 4; i++)
#pragma unroll
            for (int j = 0; j < 4; j++)
                acc[i][j] = __builtin_amdgcn_mfma_f32_16x16x32_bf16(
                    av[i], bv[j], acc[i][j], 0, 0, 0);
        p ^= 1;
    }

    // wave-private bf16 epilogue: two 32-row sub-passes through [32][68] slab
    __syncthreads();                    // all waves' last ds_reads done
    short* slab = lds + wid * 2176;     // 8 x 2176 shorts = 34.8KB < 48KB
    short* co = (short*)Co;
#pragma unroll
    for (int sub = 0; sub < 2; sub++) {
#pragma unroll
        for (int ii = 0; ii < 2; ii++) {
            int i = sub * 2 + ii;
            int srow2 = ii * 16 + quad * 4;
#pragma unroll
            for (int j = 0; j < 4; j++) {
                int scol = j * 16 + lr;
                float bb = bias ? bias[m0 + wc * 64 + scol] : 0.f;
#pragma unroll
                for (int rr = 0; rr < 4; rr++) {
                    float v = acc[i][j][rr] + bb;
                    if (ACT == 1) v = gelu_f(v);
                    slab[(srow2 + rr) * 68 + scol] = f2bs(v);
                }
            }
        }
        // within-wave LDS dependency only; compiler inserts lgkmcnt
#pragma unroll
        for (int it = 0; it < 8; it++) {
            int rl = (lane >> 4) + it * 4;          // 0..31
            int seg = lane & 15;
            uint2 vv = *(const uint2*)(slab + rl * 68 + seg * 4);
            int grow = r0 + wr * 64 + sub * 32 + rl;
            *(uint2*)(co + (size_t)grow * M + m0 + wc * 64 + seg * 4) = vv;
        }
    }
}

// ---------------- MFMA GEMM v8 (proven 128^2 config — proj fp32+RES, fc2 OUTT) ---------
template <int ACT, bool RES, typename TO, bool OUTT, int K>
__global__ __launch_bounds__(256, 4) void gemm_mfma(
    const short* __restrict__ Abf, const short* __restrict__ Bw,
    const float* __restrict__ bias, const float* __restrict__ res,
    TO* __restrict__ Co, int M, int NX)
{
    int id = blockIdx.x;
    int xcd = id & 7, slot_ = id >> 3;
    int yloc = slot_ / NX, xx = slot_ - yloc * NX;
    int y = xcd * PERXCD + yloc;
    if (y >= YTILES) return;

    __shared__ __align__(16) short lds[16896];  // 33792B: 2 x (A 8K | B 8K) bytes
    const int tid = threadIdx.x;
    const int wid = tid >> 6, lane = tid & 63;
    const int wrow = wid >> 1, wcol = wid & 1;
    const int quad = lane >> 4, lr = lane & 15;
    const int r0 = y * 128, m0 = xx * 128;

    const int srow = lane >> 2;                      // 16 rows per staging round
    const int sg   = (lane & 3) ^ ((lane >> 3) & 3); // source colgroup g^((row>>1)&3)
    const short* gA = Abf + (size_t)(r0 + wid * 32 + srow) * K + sg * 8;
    const short* gB = Bw  + (size_t)(m0 + wid * 32 + srow) * K + sg * 8;

    auto stage = [&](int k0, int p) {
        short* lA = lds + p * 8192 + wid * 1024;
        short* lB = lds + p * 8192 + 4096 + wid * 1024;
#pragma unroll
        for (int k = 0; k < 2; k++) {
            gload16(gA + k0 + (size_t)k * 16 * K, lA + k * 512);
            gload16(gB + k0 + (size_t)k * 16 * K, lB + k * 512);
        }
    };

    const int slot = (quad ^ ((lr >> 1) & 3)) * 8;   // inverse swizzle
    int fA[4], fB[4];
#pragma unroll
    for (int i = 0; i < 4; i++) {
        fA[i] = (wrow * 64 + i * 16 + lr) * 32 + slot;
        fB[i] = 4096 + (wcol * 64 + i * 16 + lr) * 32 + slot;
    }

    f32x4 acc[4][4] = {};

    stage(0, 0);
    int p = 0;
    for (int k0 = 0; k0 < K; k0 += 32) {
        __syncthreads();
        if (k0 + 32 < K) stage(k0 + 32, p ^ 1);     // overlaps compute below
        const short* As = lds + p * 8192;
        bf16x8 av[4], bv[4];
#pragma unroll
        for (int i = 0; i < 4; i++) {
            av[i] = *(const bf16x8*)(As + fA[i]);
            bv[i] = *(const bf16x8*)(As + fB[i]);
        }
#pragma unroll
        for (int i = 0; i < 4; i++)
#pragma unroll
            for (int j = 0; j < 4; j++)
                acc[i][j] = __builtin_amdgcn_mfma_f32_16x16x32_bf16(
                    av[i], bv[j], acc[i][j], 0, 0, 0);
        p ^= 1;
    }

    if constexpr (OUTT) {
        // fp32 output transposed to (B,C,HW): two passes of 64 cols via LDS
        float* Csf = (float*)lds;                   // [128][66] fp32 = 33792B
        __syncthreads();                            // all K-loop LDS reads done
#pragma unroll
        for (int pass = 0; pass < 2; pass++) {
            if (wcol == pass) {
#pragma unroll
                for (int i = 0; i < 4; i++) {
                    int lrow = wrow * 64 + i * 16 + quad * 4;
#pragma unroll
                    for (int j = 0; j < 4; j++) {
                        int lcol = j * 16 + lr;
                        int gc = m0 + pass * 64 + lcol;
                        float bb = bias ? bias[gc] : 0.f;
#pragma unroll
                        for (int rr = 0; rr < 4; rr++) {
                            float v = acc[i][j][rr] + bb;
                            if (RES)
                                v += res[(size_t)(r0 + lrow + rr) * M + gc];
                            if (ACT == 1) v = gelu_f(v);
                            Csf[(lrow + rr) * 66 + lcol] = v;
                        }
                    }
                }
            }
            __syncthreads();
            // flush: 128 lanes = 128 consecutive tokens, same channel -> coalesced
            int tok = tid & 127;
            int csel = tid >> 7;
            int gtok = r0 + tok;
            int bb2 = gtok / NTOK;
            int nn2 = gtok - bb2 * NTOK;
#pragma unroll
            for (int s = 0; s < 32; s++) {
                int cl = s * 2 + csel;
                int gcol = m0 + pass * 64 + cl;
                Co[((size_t)bb2 * CDIM + gcol) * NTOK + nn2] = Csf[tok * 66 + cl];
            }
            __syncthreads();
        }
    } else if constexpr (sizeof(TO) == 4) {
#pragma unroll
        for (int i = 0; i < 4; i++) {
            int gr = r0 + wrow * 64 + i * 16 + quad * 4;
#pragma unroll
            for (int j = 0; j < 4; j++) {
                int gc = m0 + wcol * 64 + j * 16 + lr;
                float bb = bias ? bias[gc] : 0.f;
#pragma unroll
                for (int rr = 0; rr < 4; rr++) {
                    size_t idx = (size_t)(gr + rr) * M + gc;
                    float v = acc[i][j][rr] + bb;
                    if (RES) v += res[idx];
                    if (ACT == 1) v = gelu_f(v);
                    stf((float*)&Co[idx], v);
                }
            }
        }
    } else {
        __syncthreads();                  // all LDS reads done before Cs overwrite
        short* Cs = lds;
#pragma unroll
        for (int i = 0; i < 4; i++) {
            int lrow = wrow * 64 + i * 16 + quad * 4;
#pragma unroll
            for (int j = 0; j < 4; j++) {
                int lcol = wcol * 64 + j * 16 + lr;
                float bb = bias ? bias[m0 + lcol] : 0.f;
#pragma unroll
                for (int rr = 0; rr < 4; rr++) {
                    float v = acc[i][j][rr] + bb;
                    if (ACT == 1) v = gelu_f(v);
                    Cs[(lrow + rr) * 132 + lcol] = f2bs(v);
                }
            }
        }
        __syncthreads();
        short* co = (short*)Co;
#pragma unroll
        for (int s = 0; s < 16; s++) {
            int row = s * 8 + (tid >> 5);
            int seg = tid & 31;
            uint2 vv = *(const uint2*)(Cs + row * 132 + seg * 4);
            *(uint2*)(co + (size_t)(r0 + row) * M + m0 + seg * 4) = vv;
        }
    }
}

// ---------------- channel attention: attn[b,h,d,e] = softmax_e(SCALE * sum_n k*v) ------
__global__ __launch_bounds__(256) void attn_k(
    const bf16* __restrict__ qkv, float* __restrict__ attn)
{
    int bh = blockIdx.x;
    int b = bh / NHEADS, h = bh % NHEADS;
    __shared__ float ks[64][32];
    __shared__ float vs[64][32];
    __shared__ float sm[32][33];
    int tid = threadIdx.x;
    int d = tid >> 3, e0 = (tid & 7) * 4;
    int nn = tid >> 2, q8 = (tid & 3) * 8;
    float acc[4] = {0.f, 0.f, 0.f, 0.f};
    for (int n0 = 0; n0 < NTOK; n0 += 64) {
        int n = n0 + nn;
        float kv[8], vv[8];
        if (n < NTOK) {
            const unsigned short* base =
                (const unsigned short*)qkv + ((size_t)b * NTOK + n) * (3 * CDIM);
            uint4 kq = *(const uint4*)(base + CDIM + h * HDIM + q8);
            uint4 vq = *(const uint4*)(base + 2 * CDIM + h * HDIM + q8);
            const unsigned short* kp = (const unsigned short*)&kq;
            const unsigned short* vp = (const unsigned short*)&vq;
#pragma unroll
            for (int j = 0; j < 8; j++) {
                kv[j] = ATT_SCALE * bf2f(kp[j]);
                vv[j] = bf2f(vp[j]);
            }
        } else {
#pragma unroll
            for (int j = 0; j < 8; j++) { kv[j] = 0.f; vv[j] = 0.f; }
        }
        *(float4*)&ks[nn][q8]     = make_float4(kv[0], kv[1], kv[2], kv[3]);
        *(float4*)&ks[nn][q8 + 4] = make_float4(kv[4], kv[5], kv[6], kv[7]);
        *(float4*)&vs[nn][q8]     = make_float4(vv[0], vv[1], vv[2], vv[3]);
        *(float4*)&vs[nn][q8 + 4] = make_float4(vv[4], vv[5], vv[6], vv[7]);
        __syncthreads();
#pragma unroll 8
        for (int k = 0; k < 64; k++) {
            float kd = ks[k][d];
            float4 vv4 = *(const float4*)&vs[k][e0];
            acc[0] = fmaf(kd, vv4.x, acc[0]);
            acc[1] = fmaf(kd, vv4.y, acc[1]);
            acc[2] = fmaf(kd, vv4.z, acc[2]);
            acc[3] = fmaf(kd, vv4.w, acc[3]);
        }
        __syncthreads();
    }
#pragma unroll
    for (int j = 0; j < 4; j++) sm[d][e0 + j] = acc[j];
    __syncthreads();
    if (tid < 32) {
        float mx = -1e30f;
#pragma unroll
        for (int e = 0; e < 32; e++) mx = fmaxf(mx, sm[tid][e]);
        float ssum = 0.f;
        float ex[32];
#pragma unroll
        for (int e = 0; e < 32; e++) { ex[e] = expf(sm[tid][e] - mx); ssum += ex[e]; }
        float inv = 1.f / ssum;
        float* arow = attn + ((size_t)bh * 32 + tid) * 32;
#pragma unroll
        for (int e = 0; e < 32; e++) arow[e] = ex[e] * inv;
    }
}

// ---------------- apply attention: uint4 staging, attn row in registers ----------------
__global__ __launch_bounds__(384) void apply_attn_k(
    const bf16* __restrict__ qkv, const float* __restrict__ attn,
    bf16* __restrict__ out)
{
    int b = blockIdx.x;
    int chunk = blockIdx.y;            // 14 chunks of 56 tokens
    int tid = threadIdx.x;             // 0..383
    int h = tid >> 5;
    __shared__ float qs[8][CDIM];
    float at[32];
    const float4* ap = (const float4*)(attn + ((size_t)(b * NHEADS) * 32 + tid) * 32);
#pragma unroll
    for (int e4 = 0; e4 < 8; e4++) {
        float4 v = ap[e4];
        at[e4 * 4 + 0] = v.x; at[e4 * 4 + 1] = v.y;
        at[e4 * 4 + 2] = v.z; at[e4 * 4 + 3] = v.w;
    }
    int row8 = tid / 48;               // 0..7
    int seg = tid - row8 * 48;         // 0..47
    int nbase = chunk * 56;
    for (int t0 = 0; t0 < 56; t0 += 8) {
        __syncthreads();
        {
            int n = nbase + t0 + row8;
            const unsigned short* src =
                (const unsigned short*)qkv + ((size_t)b * NTOK + n) * (3 * CDIM) + seg * 8;
            uint4 qv = *(const uint4*)src;
            const unsigned short* qp = (const unsigned short*)&qv;
            *(float4*)&qs[row8][seg * 8] =
                make_float4(bf2f(qp[0]), bf2f(qp[1]), bf2f(qp[2]), bf2f(qp[3]));
            *(float4*)&qs[row8][seg * 8 + 4] =
                make_float4(bf2f(qp[4]), bf2f(qp[5]), bf2f(qp[6]), bf2f(qp[7]));
        }
        __syncthreads();
#pragma unroll
        for (int i = 0; i < 8; i++) {
            const float4* q4 = (const float4*)&qs[i][h * 32];
            float s = 0.f;
#pragma unroll
            for (int e4 = 0; e4 < 8; e4++) {
                float4 qv = q4[e4];
                s = fmaf(at[e4 * 4 + 0], qv.x, s);
                s = fmaf(at[e4 * 4 + 1], qv.y, s);
                s = fmaf(at[e4 * 4 + 2], qv.z, s);
                s = fmaf(at[e4 * 4 + 3], qv.w, s);
            }
            int n = nbase + t0 + i;
            out[((size_t)b * NTOK + n) * CDIM + tid] = __float2bfloat16(s);
        }
    }
}

extern "C" void kernel_launch(void* const* d_in, const int* in_sizes, int n_in,
                              void* d_out, int out_size, void* d_ws, size_t ws_size,
                              hipStream_t stream) {
    const float* x      = (const float*)d_in[0];
    const float* cpe1_w = (const float*)d_in[1];
    const float* cpe1_b = (const float*)d_in[2];
    const float* n1g    = (const float*)d_in[3];
    const float* n1b    = (const float*)d_in[4];
    const float* qkv_w  = (const float*)d_in[5];
    const float* proj_w = (const float*)d_in[6];
    const float* proj_b = (const float*)d_in[7];
    const float* cpe2_w = (const float*)d_in[8];
    const float* cpe2_b = (const float*)d_in[9];
    const float* n2g    = (const float*)d_in[10];
    const float* n2b    = (const float*)d_in[11];
    const float* fc1_w  = (const float*)d_in[12];
    const float* fc1_b  = (const float*)d_in[13];
    const float* fc2_w  = (const float*)d_in[14];
    const float* fc2_b  = (const float*)d_in[15];

    const size_t A = (size_t)BN * CDIM;        // 9,633,792
    const size_t HA = A / 2;

    // bf16 weights contiguous at front of ws
    bf16* wqkv  = (bf16*)d_ws;                 // 442368
    bf16* wproj = wqkv + 442368;               // 147456
    bf16* wfc1  = wproj + 147456;              // 589824
    bf16* wfc2  = wfc1 + 589824;               // 589824
    float* base = (float*)d_ws + 884736;

    float* xt        = base;                   // [0, A)        residual stream
    bf16*  curb      = (bf16*)(base + A);      // [A, 1.5A)     LN1 out (bf16)
    bf16*  ylnb      = (bf16*)(base + A);      // phase-2 reuse LN2 out (bf16)
    bf16*  qkvb      = (bf16*)(base + A + HA); // [1.5A, 3A)    qkv (bf16, 3A elems)
    float* x3        = base + A + HA;          // phase-2 reuse [1.5A, 2.5A)
    bf16*  h1        = (bf16*)(base + A + HA + A); // [2.5A, 4.5A) fc1 out (bf16)
    float* attnm     = base + 3 * A;           // [3A, +393216)
    bf16*  attn_outb = (bf16*)(base + 3 * A + 393216);
    float* cpe2_wt   = base + (A * 9) / 2;     // [4.5A, +3456) transposed taps

    const int GEMM_GRID3  = 8 * PERXCD * 3;    // 600
    const int G256_9  = 8 * PERXCD2 * 9;       // 936
    const int G256_12 = 8 * PERXCD2 * 12;      // 1248

    // 0. weight conversion fp32 -> bf16 + cpe2 tap transpose (one launch)
    prep_k<<<6926, 256, 0, stream>>>(qkv_w, proj_w, fc1_w, fc2_w, wqkv,
                                     cpe2_w, cpe2_wt);

    // 1. fused cpe1 + residual + transpose v3 (lanes-along-c, 1 barrier, 18KB LDS)
    cpe1_tr_v3<<<dim3(CDIM / 32, 13, BBATCH), 256, 0, stream>>>(
        x, cpe1_w, cpe1_b, xt);
    // 2. LN1 -> bf16 (float4, 32 lanes/token)
    ln1_k<<<BN / 8, 256, 0, stream>>>(xt, n1g, n1b, curb);
    // 3. qkv GEMM (256x128 tile, bf16 out)
    gemm256<0, 384><<<G256_9, 512, 0, stream>>>(
        (const short*)curb, (const short*)wqkv, nullptr, qkvb, 1152, 9);
    // 4. channel attention matrices + softmax
    attn_k<<<BBATCH * NHEADS, 256, 0, stream>>>(qkvb, attnm);
    // 5. apply attention to q (out bf16)
    apply_attn_k<<<dim3(BBATCH, 14), 384, 0, stream>>>(qkvb, attnm, attn_outb);
    // 6. proj GEMM + bias + residual (in-place into xt) — proven 128^2 kernel
    gemm_mfma<0, true, float, false, 384><<<GEMM_GRID3, 256, 0, stream>>>(
        (const short*)attn_outb, (const short*)wproj, proj_b, xt, xt, 384, 3);
    // 7+8. fused cpe2 + residual + LN2 (float4; writes x3 fp32 and ylnb bf16)
    cpe2_ln_fused<<<BN / 8, 256, 0, stream>>>(xt, cpe2_wt, cpe2_b, n2g, n2b,
                                              x3, ylnb);
    // 9. fc1 + bias + GELU (256x128 tile, bf16 out)
    gemm256<1, 384><<<G256_12, 512, 0, stream>>>(
        (const short*)ylnb, (const short*)wfc1, fc1_b, h1, 1536, 12);
    // 10. fc2 + bias + residual(x3), output directly transposed to (B,C,H,W)
    gemm_mfma<0, true, float, true, 1536><<<GEMM_GRID3, 256, 0, stream>>>(
        (const short*)h1, (const short*)wfc2, fc2_b, x3, (float*)d_out, 384, 3);
}

// Round 11
// 399.726 us; speedup vs baseline: 1.0105x; 1.0105x over previous
//
#include <hip/hip_runtime.h>
#include <hip/hip_bf16.h>

#define CDIM 384
#define NHEADS 12
#define HDIM 32
#define HIDDEN 1536
#define BBATCH 32
#define HH 28
#define WW 28
#define NTOK 784
#define BN (BBATCH * NTOK)   // 25088
#define LN_EPS 1e-5f
#define ATT_SCALE 0.17677669529663687f
#define YTILES 196           // BN / 128
#define PERXCD 25            // ceil(YTILES / 8)

typedef __hip_bfloat16 bf16;
typedef __attribute__((ext_vector_type(8))) short bf16x8;
typedef __attribute__((ext_vector_type(4))) float f32x4;

__device__ __forceinline__ void stf(float* p, float v) { *p = v; }
__device__ __forceinline__ void stf(bf16* p, float v) { *p = __float2bfloat16(v); }

__device__ __forceinline__ short f2bs(float v) {
    bf16 t = __float2bfloat16(v);
    return *reinterpret_cast<short*>(&t);
}

__device__ __forceinline__ float bf2f(unsigned short u) {
    return __uint_as_float(((unsigned)u) << 16);
}

// tanh-form GELU via sigmoid; max |diff| vs exact ~3e-4, well inside tolerance.
__device__ __forceinline__ float gelu_f(float x) {
    float u = x * (0.7978845608f + 0.0356774081f * x * x);
    float e = __expf(-2.f * u);
    return x / (1.f + e);
}

__device__ __forceinline__ void gload16(const void* g, void* l) {
    __builtin_amdgcn_global_load_lds(
        (const __attribute__((address_space(1))) unsigned int*)g,
        (__attribute__((address_space(3))) unsigned int*)l, 16, 0, 0);
}

// ---------------- fp32 -> bf16 weight conversion + cpe2 tap transpose, one launch ------
__global__ __launch_bounds__(256) void prep_k(
    const float* __restrict__ w0, const float* __restrict__ w1,
    const float* __restrict__ w2, const float* __restrict__ w3,
    bf16* __restrict__ dst, const float* __restrict__ cw,
    float* __restrict__ cwt)
{
    int blk = blockIdx.x;
    if (blk >= 6912) {                         // tail blocks: cpe2 (C,9)->(9,C)
        int i = (blk - 6912) * 256 + threadIdx.x;
        if (i < 9 * CDIM) {
            int k = i / CDIM, c = i % CDIM;
            cwt[i] = cw[c * 9 + k];
        }
        return;
    }
    int i = blk * 256 + threadIdx.x;           // 0..1769471, dst regions contiguous
    const float* src; int off;
    if (i < 442368)       { src = w0; off = i; }
    else if (i < 589824)  { src = w1; off = i - 442368; }
    else if (i < 1179648) { src = w2; off = i - 589824; }
    else                  { src = w3; off = i - 1179648; }
    dst[i] = __float2bfloat16(src[off]);
}

// ---------------- fused cpe1 + residual + transpose v3: lanes-along-c, 1 barrier -------
__global__ __launch_bounds__(256) void cpe1_tr_v3(
    const float* __restrict__ x, const float* __restrict__ w,
    const float* __restrict__ bias, float* __restrict__ xt)
{
    __shared__ float sm[32][130];   // 16.6 KB
    __shared__ float wls[32][10];   // per-block weight cache (stride 10 -> 2-way max)
    __shared__ float bls[32];
    int b = blockIdx.z;
    int n0 = blockIdx.y * 64;
    int c0 = blockIdx.x * 32;
    int tid = threadIdx.x;          // 256
    int nf0 = (n0 - 32) >> 2;       // window start in float4 units (may be negative)

    for (int i = tid; i < 288; i += 256) wls[i / 9][i % 9] = w[c0 * 9 + i];
    if (tid < 32) bls[tid] = bias[c0 + tid];

    const float4* xb = (const float4*)(x + ((size_t)b * CDIM + c0) * NTOK);
#pragma unroll
    for (int i = 0; i < 4; i++) {
        int q = tid + i * 256;      // 0..1023
        int row = q >> 5, c4 = q & 31;
        int nf = nf0 + c4;
        float4 v = {0.f, 0.f, 0.f, 0.f};
        if ((unsigned)nf < (NTOK >> 2)) v = xb[(size_t)row * (NTOK >> 2) + nf];
        float2* p = (float2*)&sm[row][c4 * 4];    // 8B-aligned (130*4=520 % 8 == 0)
        p[0] = make_float2(v.x, v.y);
        p[1] = make_float2(v.z, v.w);
    }
    __syncthreads();

    int c = tid & 31;
    int tsub = tid >> 5;            // 0..7
    float wr[9];
#pragma unroll
    for (int k = 0; k < 9; k++) wr[k] = wls[c][k];
    float bb = bls[c];
    const float* s = sm[c];
#pragma unroll
    for (int it = 0; it < 8; it++) {
        int tok = it * 8 + tsub;
        int n = n0 + tok;
        if (n < NTOK) {
            int h = n / WW, wc = n % WW;
            bool hm = h > 0, hp = h < HH - 1, wm = wc > 0, wpv = wc < WW - 1;
            int l = 32 + tok;
            float a = wr[4] * s[l];
            if (hm)        a += wr[1] * s[l - WW];
            if (hp)        a += wr[7] * s[l + WW];
            if (wm)        a += wr[3] * s[l - 1];
            if (wpv)       a += wr[5] * s[l + 1];
            if (hm && wm)  a += wr[0] * s[l - WW - 1];
            if (hm && wpv) a += wr[2] * s[l - WW + 1];
            if (hp && wm)  a += wr[6] * s[l + WW - 1];
            if (hp && wpv) a += wr[8] * s[l + WW + 1];
            xt[((size_t)b * NTOK + n) * CDIM + c0 + c] = s[l] + a + bb;
        }
    }
}

// ---------------- LN1: 32 lanes per token, float4 loads, ushort4 bf16 stores -----------
__global__ __launch_bounds__(256) void ln1_k(
    const float* __restrict__ in, const float* __restrict__ g,
    const float* __restrict__ b, bf16* __restrict__ out)
{
    int tid = threadIdx.x;
    int l = tid & 31;
    size_t tok = (size_t)blockIdx.x * 8 + (tid >> 5);
    const float4* row = (const float4*)(in + tok * CDIM);
    float4 v[3];
    float s = 0.f;
#pragma unroll
    for (int j = 0; j < 3; j++) {
        v[j] = row[l + j * 32];
        s += v[j].x + v[j].y + v[j].z + v[j].w;
    }
#pragma unroll
    for (int off = 16; off >= 1; off >>= 1) s += __shfl_xor(s, off);
    float mu = s * (1.f / CDIM);
    float q = 0.f;
#pragma unroll
    for (int j = 0; j < 3; j++) {
        float dx = v[j].x - mu, dy = v[j].y - mu;
        float dz = v[j].z - mu, dw = v[j].w - mu;
        q += dx * dx + dy * dy + dz * dz + dw * dw;
    }
#pragma unroll
    for (int off = 16; off >= 1; off >>= 1) q += __shfl_xor(q, off);
    float rs = rsqrtf(q * (1.f / CDIM) + LN_EPS);
    const float4* g4 = (const float4*)g;
    const float4* b4 = (const float4*)b;
    ushort4* o4 = (ushort4*)(out + tok * CDIM);
#pragma unroll
    for (int j = 0; j < 3; j++) {
        int idx = l + j * 32;
        float4 gv = g4[idx], bv = b4[idx];
        ushort4 r;
        r.x = (unsigned short)f2bs((v[j].x - mu) * rs * gv.x + bv.x);
        r.y = (unsigned short)f2bs((v[j].y - mu) * rs * gv.y + bv.y);
        r.z = (unsigned short)f2bs((v[j].z - mu) * rs * gv.z + bv.z);
        r.w = (unsigned short)f2bs((v[j].w - mu) * rs * gv.w + bv.w);
        o4[idx] = r;
    }
}

// ---------------- fused cpe2 + residual + LN2: 32 lanes per token, float4 --------------
__global__ __launch_bounds__(256) void cpe2_ln_fused(
    const float* __restrict__ xin, const float* __restrict__ wt,
    const float* __restrict__ cbias, const float* __restrict__ g,
    const float* __restrict__ b, float* __restrict__ x3,
    bf16* __restrict__ lnout)
{
    __shared__ float wts[9 * CDIM];
    int tid = threadIdx.x;
    for (int i = tid; i < 864; i += 256)
        ((float4*)wts)[i] = ((const float4*)wt)[i];
    __syncthreads();
    int l = tid & 31;
    size_t tok = (size_t)blockIdx.x * 8 + (tid >> 5);
    int n = (int)(tok % NTOK);
    int h = n / WW, wc = n % WW;
    bool hm = h > 0, hp = h < HH - 1, wm = wc > 0, wpv = wc < WW - 1;
    const float* row = xin + tok * CDIM;
    const float4* w4 = (const float4*)wts;
    float4 ctr[3], acc[3];
#pragma unroll
    for (int j = 0; j < 3; j++) {
        int idx = l + j * 32;
        ctr[j] = ((const float4*)row)[idx];
        float4 ww = w4[4 * 96 + idx];
        acc[j].x = ww.x * ctr[j].x; acc[j].y = ww.y * ctr[j].y;
        acc[j].z = ww.z * ctr[j].z; acc[j].w = ww.w * ctr[j].w;
    }
#define TAP(k, cond, dn)                                                     \
    if (cond) {                                                              \
        const float4* rp = (const float4*)(row + (dn) * CDIM);               \
        _Pragma("unroll")                                                    \
        for (int j = 0; j < 3; j++) {                                        \
            int idx = l + j * 32;                                            \
            float4 vv = rp[idx];                                             \
            float4 ww = w4[(k) * 96 + idx];                                  \
            acc[j].x = fmaf(ww.x, vv.x, acc[j].x);                           \
            acc[j].y = fmaf(ww.y, vv.y, acc[j].y);                           \
            acc[j].z = fmaf(ww.z, vv.z, acc[j].z);                           \
            acc[j].w = fmaf(ww.w, vv.w, acc[j].w);                           \
        }                                                                    \
    }
    TAP(0, hm && wm,   -WW - 1)
    TAP(1, hm,         -WW)
    TAP(2, hm && wpv,  -WW + 1)
    TAP(3, wm,         -1)
    TAP(5, wpv,        1)
    TAP(6, hp && wm,   WW - 1)
    TAP(7, hp,         WW)
    TAP(8, hp && wpv,  WW + 1)
#undef TAP
    float s = 0.f;
    float4 val[3];
    float4* x3r = (float4*)(x3 + tok * CDIM);
#pragma unroll
    for (int j = 0; j < 3; j++) {
        int idx = l + j * 32;
        float4 cb = ((const float4*)cbias)[idx];
        val[j].x = ctr[j].x + acc[j].x + cb.x;
        val[j].y = ctr[j].y + acc[j].y + cb.y;
        val[j].z = ctr[j].z + acc[j].z + cb.z;
        val[j].w = ctr[j].w + acc[j].w + cb.w;
        x3r[idx] = val[j];
        s += val[j].x + val[j].y + val[j].z + val[j].w;
    }
#pragma unroll
    for (int off = 16; off >= 1; off >>= 1) s += __shfl_xor(s, off);
    float mu = s * (1.f / CDIM);
    float q = 0.f;
#pragma unroll
    for (int j = 0; j < 3; j++) {
        float dx = val[j].x - mu, dy = val[j].y - mu;
        float dz = val[j].z - mu, dw = val[j].w - mu;
        q += dx * dx + dy * dy + dz * dz + dw * dw;
    }
#pragma unroll
    for (int off = 16; off >= 1; off >>= 1) q += __shfl_xor(q, off);
    float rs = rsqrtf(q * (1.f / CDIM) + LN_EPS);
    const float4* g4 = (const float4*)g;
    const float4* b4 = (const float4*)b;
    ushort4* o4 = (ushort4*)(lnout + tok * CDIM);
#pragma unroll
    for (int j = 0; j < 3; j++) {
        int idx = l + j * 32;
        float4 gv = g4[idx], bv = b4[idx];
        ushort4 r;
        r.x = (unsigned short)f2bs((val[j].x - mu) * rs * gv.x + bv.x);
        r.y = (unsigned short)f2bs((val[j].y - mu) * rs * gv.y + bv.y);
        r.z = (unsigned short)f2bs((val[j].z - mu) * rs * gv.z + bv.z);
        r.w = (unsigned short)f2bs((val[j].w - mu) * rs * gv.w + bv.w);
        o4[idx] = r;
    }
}

// ---------------- MFMA GEMM v8 (best measured config — frozen) -------------------------
// 128x128 tile, 4 waves, BK=32, 2-buf, 33792B LDS -> 4 blocks/CU; compile-time K.
// Six structural variants (BK=64, 3-buf counted-vmcnt, B-in-reg, 8-phase 256x128,
// 2-pass epilogue, 256x128 2-phase) ALL regressed vs this config. ~66us/fc1-class
// dispatch is the plateau at K=384/1536 tile depth. Swizzle measured 0 conflicts.
template <int ACT, bool RES, typename TO, bool OUTT, int K>
__global__ __launch_bounds__(256, 4) void gemm_mfma(
    const short* __restrict__ Abf, const short* __restrict__ Bw,
    const float* __restrict__ bias, const float* __restrict__ res,
    TO* __restrict__ Co, int M, int NX)
{
    int id = blockIdx.x;
    int xcd = id & 7, slot_ = id >> 3;
    int yloc = slot_ / NX, xx = slot_ - yloc * NX;
    int y = xcd * PERXCD + yloc;
    if (y >= YTILES) return;

    __shared__ __align__(16) short lds[16896];  // 33792B: 2 x (A 8K | B 8K) bytes
    const int tid = threadIdx.x;
    const int wid = tid >> 6, lane = tid & 63;
    const int wrow = wid >> 1, wcol = wid & 1;
    const int quad = lane >> 4, lr = lane & 15;
    const int r0 = y * 128, m0 = xx * 128;

    const int srow = lane >> 2;                      // 16 rows per staging round
    const int sg   = (lane & 3) ^ ((lane >> 3) & 3); // source colgroup g^((row>>1)&3)
    const short* gA = Abf + (size_t)(r0 + wid * 32 + srow) * K + sg * 8;
    const short* gB = Bw  + (size_t)(m0 + wid * 32 + srow) * K + sg * 8;

    auto stage = [&](int k0, int p) {
        short* lA = lds + p * 8192 + wid * 1024;
        short* lB = lds + p * 8192 + 4096 + wid * 1024;
#pragma unroll
        for (int k = 0; k < 2; k++) {
            gload16(gA + k0 + (size_t)k * 16 * K, lA + k * 512);
            gload16(gB + k0 + (size_t)k * 16 * K, lB + k * 512);
        }
    };

    const int slot = (quad ^ ((lr >> 1) & 3)) * 8;   // inverse swizzle
    int fA[4], fB[4];
#pragma unroll
    for (int i = 0; i < 4; i++) {
        fA[i] = (wrow * 64 + i * 16 + lr) * 32 + slot;
        fB[i] = 4096 + (wcol * 64 + i * 16 + lr) * 32 + slot;
    }

    f32x4 acc[4][4] = {};

    stage(0, 0);
    int p = 0;
    for (int k0 = 0; k0 < K; k0 += 32) {
        __syncthreads();
        if (k0 + 32 < K) stage(k0 + 32, p ^ 1);     // overlaps compute below
        const short* As = lds + p * 8192;
        bf16x8 av[4], bv[4];
#pragma unroll
        for (int i = 0; i < 4; i++) {
            av[i] = *(const bf16x8*)(As + fA[i]);
            bv[i] = *(const bf16x8*)(As + fB[i]);
        }
#pragma unroll
        for (int i = 0; i < 4; i++)
#pragma unroll
            for (int j = 0; j < 4; j++)
                acc[i][j] = __builtin_amdgcn_mfma_f32_16x16x32_bf16(
                    av[i], bv[j], acc[i][j], 0, 0, 0);
        p ^= 1;
    }

    if constexpr (OUTT) {
        // fp32 output transposed to (B,C,HW): two passes of 64 cols via LDS
        float* Csf = (float*)lds;                   // [128][66] fp32 = 33792B
        __syncthreads();                            // all K-loop LDS reads done
#pragma unroll
        for (int pass = 0; pass < 2; pass++) {
            if (wcol == pass) {
#pragma unroll
                for (int i = 0; i < 4; i++) {
                    int lrow = wrow * 64 + i * 16 + quad * 4;
#pragma unroll
                    for (int j = 0; j < 4; j++) {
                        int lcol = j * 16 + lr;
                        int gc = m0 + pass * 64 + lcol;
                        float bb = bias ? bias[gc] : 0.f;
#pragma unroll
                        for (int rr = 0; rr < 4; rr++) {
                            float v = acc[i][j][rr] + bb;
                            if (RES)
                                v += res[(size_t)(r0 + lrow + rr) * M + gc];
                            if (ACT == 1) v = gelu_f(v);
                            Csf[(lrow + rr) * 66 + lcol] = v;
                        }
                    }
                }
            }
            __syncthreads();
            // flush: 128 lanes = 128 consecutive tokens, same channel -> coalesced
            int tok = tid & 127;
            int csel = tid >> 7;
            int gtok = r0 + tok;
            int bb2 = gtok / NTOK;
            int nn2 = gtok - bb2 * NTOK;
#pragma unroll
            for (int s = 0; s < 32; s++) {
                int cl = s * 2 + csel;
                int gcol = m0 + pass * 64 + cl;
                Co[((size_t)bb2 * CDIM + gcol) * NTOK + nn2] = Csf[tok * 66 + cl];
            }
            __syncthreads();
        }
    } else if constexpr (sizeof(TO) == 4) {
#pragma unroll
        for (int i = 0; i < 4; i++) {
            int gr = r0 + wrow * 64 + i * 16 + quad * 4;
#pragma unroll
            for (int j = 0; j < 4; j++) {
                int gc = m0 + wcol * 64 + j * 16 + lr;
                float bb = bias ? bias[gc] : 0.f;
#pragma unroll
                for (int rr = 0; rr < 4; rr++) {
                    size_t idx = (size_t)(gr + rr) * M + gc;
                    float v = acc[i][j][rr] + bb;
                    if (RES) v += res[idx];
                    if (ACT == 1) v = gelu_f(v);
                    stf((float*)&Co[idx], v);
                }
            }
        }
    } else {
        __syncthreads();                  // all LDS reads done before Cs overwrite
        short* Cs = lds;
#pragma unroll
        for (int i = 0; i < 4; i++) {
            int lrow = wrow * 64 + i * 16 + quad * 4;
#pragma unroll
            for (int j = 0; j < 4; j++) {
                int lcol = wcol * 64 + j * 16 + lr;
                float bb = bias ? bias[m0 + lcol] : 0.f;
#pragma unroll
                for (int rr = 0; rr < 4; rr++) {
                    float v = acc[i][j][rr] + bb;
                    if (ACT == 1) v = gelu_f(v);
                    Cs[(lrow + rr) * 132 + lcol] = f2bs(v);
                }
            }
        }
        __syncthreads();
        short* co = (short*)Co;
#pragma unroll
        for (int s = 0; s < 16; s++) {
            int row = s * 8 + (tid >> 5);
            int seg = tid & 31;
            uint2 vv = *(const uint2*)(Cs + row * 132 + seg * 4);
            *(uint2*)(co + (size_t)(r0 + row) * M + m0 + seg * 4) = vv;
        }
    }
}

// ---------------- channel attention part 1: per-quarter partial K^T V ------------------
// attn_k was 384 blocks (1.5/CU) x 26 barriers — same latency-bound disease as the
// old cpe1. Split the 784-token sum into 4 quarters of 196: grid (384,4) = 1536
// blocks, 4 stage-iters (8 barriers) each; partials written as float4 (no softmax
// stage, no sm LDS). attn_sm_k reduces + softmaxes.
__global__ __launch_bounds__(256) void attn_part_k(
    const bf16* __restrict__ qkv, float* __restrict__ part)
{
    int bh = blockIdx.x;
    int q4 = blockIdx.y;
    int b = bh / NHEADS, h = bh % NHEADS;
    __shared__ float ks[64][32];
    __shared__ float vs[64][32];
    int tid = threadIdx.x;
    int d = tid >> 3, e0 = (tid & 7) * 4;
    int nn = tid >> 2, q8 = (tid & 3) * 8;
    int nstart = q4 * 196, nend = nstart + 196;
    float acc[4] = {0.f, 0.f, 0.f, 0.f};
    for (int n0 = nstart; n0 < nend; n0 += 64) {
        int n = n0 + nn;
        float kv[8], vv[8];
        if (n < nend) {
            const unsigned short* base =
                (const unsigned short*)qkv + ((size_t)b * NTOK + n) * (3 * CDIM);
            uint4 kq = *(const uint4*)(base + CDIM + h * HDIM + q8);
            uint4 vq = *(const uint4*)(base + 2 * CDIM + h * HDIM + q8);
            const unsigned short* kp = (const unsigned short*)&kq;
            const unsigned short* vp = (const unsigned short*)&vq;
#pragma unroll
            for (int j = 0; j < 8; j++) {
                kv[j] = ATT_SCALE * bf2f(kp[j]);
                vv[j] = bf2f(vp[j]);
            }
        } else {
#pragma unroll
            for (int j = 0; j < 8; j++) { kv[j] = 0.f; vv[j] = 0.f; }
        }
        *(float4*)&ks[nn][q8]     = make_float4(kv[0], kv[1], kv[2], kv[3]);
        *(float4*)&ks[nn][q8 + 4] = make_float4(kv[4], kv[5], kv[6], kv[7]);
        *(float4*)&vs[nn][q8]     = make_float4(vv[0], vv[1], vv[2], vv[3]);
        *(float4*)&vs[nn][q8 + 4] = make_float4(vv[4], vv[5], vv[6], vv[7]);
        __syncthreads();
#pragma unroll 8
        for (int k = 0; k < 64; k++) {
            float kd = ks[k][d];
            float4 vv4 = *(const float4*)&vs[k][e0];
            acc[0] = fmaf(kd, vv4.x, acc[0]);
            acc[1] = fmaf(kd, vv4.y, acc[1]);
            acc[2] = fmaf(kd, vv4.z, acc[2]);
            acc[3] = fmaf(kd, vv4.w, acc[3]);
        }
        __syncthreads();
    }
    *(float4*)(part + ((((size_t)q4 * 384) + bh) * 32 + d) * 32 + e0) =
        make_float4(acc[0], acc[1], acc[2], acc[3]);
}

// ---------------- channel attention part 2: reduce 4 partials + softmax ----------------
__global__ __launch_bounds__(256) void attn_sm_k(
    const float* __restrict__ part, float* __restrict__ attn)
{
    int tid = threadIdx.x;
    int bh = blockIdx.x * 8 + (tid >> 5);
    int d = tid & 31;
    const float4* p0 = (const float4*)(part + ((size_t)bh * 32 + d) * 32);
    float4 a[8];
#pragma unroll
    for (int j = 0; j < 8; j++) a[j] = p0[j];
#pragma unroll
    for (int q = 1; q < 4; q++) {
        const float4* pq = (const float4*)(part + (size_t)q * 393216 +
                                           ((size_t)bh * 32 + d) * 32);
#pragma unroll
        for (int j = 0; j < 8; j++) {
            float4 v = pq[j];
            a[j].x += v.x; a[j].y += v.y; a[j].z += v.z; a[j].w += v.w;
        }
    }
    float row[32];
#pragma unroll
    for (int j = 0; j < 8; j++) {
        row[4 * j]     = a[j].x; row[4 * j + 1] = a[j].y;
        row[4 * j + 2] = a[j].z; row[4 * j + 3] = a[j].w;
    }
    float mx = -1e30f;
#pragma unroll
    for (int e = 0; e < 32; e++) mx = fmaxf(mx, row[e]);
    float ssum = 0.f;
#pragma unroll
    for (int e = 0; e < 32; e++) { row[e] = expf(row[e] - mx); ssum += row[e]; }
    float inv = 1.f / ssum;
    float4* arow = (float4*)(attn + ((size_t)bh * 32 + d) * 32);
#pragma unroll
    for (int j = 0; j < 8; j++)
        arow[j] = make_float4(row[4 * j] * inv, row[4 * j + 1] * inv,
                              row[4 * j + 2] * inv, row[4 * j + 3] * inv);
}

// ---------------- apply attention: uint4 staging, attn row in registers ----------------
__global__ __launch_bounds__(384) void apply_attn_k(
    const bf16* __restrict__ qkv, const float* __restrict__ attn,
    bf16* __restrict__ out)
{
    int b = blockIdx.x;
    int chunk = blockIdx.y;            // 14 chunks of 56 tokens
    int tid = threadIdx.x;             // 0..383
    int h = tid >> 5;
    __shared__ float qs[8][CDIM];
    float at[32];
    const float4* ap = (const float4*)(attn + ((size_t)(b * NHEADS) * 32 + tid) * 32);
#pragma unroll
    for (int e4 = 0; e4 < 8; e4++) {
        float4 v = ap[e4];
        at[e4 * 4 + 0] = v.x; at[e4 * 4 + 1] = v.y;
        at[e4 * 4 + 2] = v.z; at[e4 * 4 + 3] = v.w;
    }
    int row8 = tid / 48;               // 0..7
    int seg = tid - row8 * 48;         // 0..47
    int nbase = chunk * 56;
    for (int t0 = 0; t0 < 56; t0 += 8) {
        __syncthreads();
        {
            int n = nbase + t0 + row8;
            const unsigned short* src =
                (const unsigned short*)qkv + ((size_t)b * NTOK + n) * (3 * CDIM) + seg * 8;
            uint4 qv = *(const uint4*)src;
            const unsigned short* qp = (const unsigned short*)&qv;
            *(float4*)&qs[row8][seg * 8] =
                make_float4(bf2f(qp[0]), bf2f(qp[1]), bf2f(qp[2]), bf2f(qp[3]));
            *(float4*)&qs[row8][seg * 8 + 4] =
                make_float4(bf2f(qp[4]), bf2f(qp[5]), bf2f(qp[6]), bf2f(qp[7]));
        }
        __syncthreads();
#pragma unroll
        for (int i = 0; i < 8; i++) {
            const float4* q4 = (const float4*)&qs[i][h * 32];
            float s = 0.f;
#pragma unroll
            for (int e4 = 0; e4 < 8; e4++) {
                float4 qv = q4[e4];
                s = fmaf(at[e4 * 4 + 0], qv.x, s);
                s = fmaf(at[e4 * 4 + 1], qv.y, s);
                s = fmaf(at[e4 * 4 + 2], qv.z, s);
                s = fmaf(at[e4 * 4 + 3], qv.w, s);
            }
            int n = nbase + t0 + i;
            out[((size_t)b * NTOK + n) * CDIM + tid] = __float2bfloat16(s);
        }
    }
}

extern "C" void kernel_launch(void* const* d_in, const int* in_sizes, int n_in,
                              void* d_out, int out_size, void* d_ws, size_t ws_size,
                              hipStream_t stream) {
    const float* x      = (const float*)d_in[0];
    const float* cpe1_w = (const float*)d_in[1];
    const float* cpe1_b = (const float*)d_in[2];
    const float* n1g    = (const float*)d_in[3];
    const float* n1b    = (const float*)d_in[4];
    const float* qkv_w  = (const float*)d_in[5];
    const float* proj_w = (const float*)d_in[6];
    const float* proj_b = (const float*)d_in[7];
    const float* cpe2_w = (const float*)d_in[8];
    const float* cpe2_b = (const float*)d_in[9];
    const float* n2g    = (const float*)d_in[10];
    const float* n2b    = (const float*)d_in[11];
    const float* fc1_w  = (const float*)d_in[12];
    const float* fc1_b  = (const float*)d_in[13];
    const float* fc2_w  = (const float*)d_in[14];
    const float* fc2_b  = (const float*)d_in[15];

    const size_t A = (size_t)BN * CDIM;        // 9,633,792
    const size_t HA = A / 2;

    // bf16 weights contiguous at front of ws
    bf16* wqkv  = (bf16*)d_ws;                 // 442368
    bf16* wproj = wqkv + 442368;               // 147456
    bf16* wfc1  = wproj + 147456;              // 589824
    bf16* wfc2  = wfc1 + 589824;               // 589824
    float* base = (float*)d_ws + 884736;

    float* xt        = base;                   // [0, A)        residual stream
    bf16*  curb      = (bf16*)(base + A);      // [A, 1.5A)     LN1 out (bf16)
    bf16*  ylnb      = (bf16*)(base + A);      // phase-2 reuse LN2 out (bf16)
    bf16*  qkvb      = (bf16*)(base + A + HA); // [1.5A, 3A)    qkv (bf16, 3A elems)
    float* x3        = base + A + HA;          // phase-2 reuse [1.5A, 2.5A)
    bf16*  h1        = (bf16*)(base + A + HA + A); // [2.5A, 4.5A) fc1 out (bf16)
    float* attnm     = base + 3 * A;           // [3A, +393216)
    bf16*  attn_outb = (bf16*)(base + 3 * A + 393216);
    float* attn_part = base + (A * 7) / 2 + 393216; // [3.5A+.., +1.57M) in h1 ph-2 zone
    float* cpe2_wt   = base + (A * 9) / 2;     // [4.5A, +3456) transposed taps

    const int GEMM_GRID3  = 8 * PERXCD * 3;    // 600
    const int GEMM_GRID9  = 8 * PERXCD * 9;    // 1800
    const int GEMM_GRID12 = 8 * PERXCD * 12;   // 2400

    // 0. weight conversion fp32 -> bf16 + cpe2 tap transpose (one launch)
    prep_k<<<6926, 256, 0, stream>>>(qkv_w, proj_w, fc1_w, fc2_w, wqkv,
                                     cpe2_w, cpe2_wt);

    // 1. fused cpe1 + residual + transpose v3 (lanes-along-c, 1 barrier, 18KB LDS)
    cpe1_tr_v3<<<dim3(CDIM / 32, 13, BBATCH), 256, 0, stream>>>(
        x, cpe1_w, cpe1_b, xt);
    // 2. LN1 -> bf16 (float4, 32 lanes/token)
    ln1_k<<<BN / 8, 256, 0, stream>>>(xt, n1g, n1b, curb);
    // 3. qkv GEMM (proven 128^2 kernel)
    gemm_mfma<0, false, bf16, false, 384><<<GEMM_GRID9, 256, 0, stream>>>(
        (const short*)curb, (const short*)wqkv, nullptr, nullptr, qkvb, 1152, 9);
    // 4a. channel attention partials (4 quarters, 1536 blocks)
    attn_part_k<<<dim3(BBATCH * NHEADS, 4), 256, 0, stream>>>(qkvb, attn_part);
    // 4b. reduce + softmax
    attn_sm_k<<<48, 256, 0, stream>>>(attn_part, attnm);
    // 5. apply attention to q (out bf16)
    apply_attn_k<<<dim3(BBATCH, 14), 384, 0, stream>>>(qkvb, attnm, attn_outb);
    // 6. proj GEMM + bias + residual (in-place into xt)
    gemm_mfma<0, true, float, false, 384><<<GEMM_GRID3, 256, 0, stream>>>(
        (const short*)attn_outb, (const short*)wproj, proj_b, xt, xt, 384, 3);
    // 7+8. fused cpe2 + residual + LN2 (float4; writes x3 fp32 and ylnb bf16)
    cpe2_ln_fused<<<BN / 8, 256, 0, stream>>>(xt, cpe2_wt, cpe2_b, n2g, n2b,
                                              x3, ylnb);
    // 9. fc1 + bias + GELU (proven 128^2 kernel)
    gemm_mfma<1, false, bf16, false, 384><<<GEMM_GRID12, 256, 0, stream>>>(
        (const short*)ylnb, (const short*)wfc1, fc1_b, nullptr, h1, 1536, 12);
    // 10. fc2 + bias + residual(x3), output directly transposed to (B,C,H,W)
    gemm_mfma<0, true, float, true, 1536><<<GEMM_GRID3, 256, 0, stream>>>(
        (const short*)h1, (const short*)wfc2, fc2_b, x3, (float*)d_out, 384, 3);
}